// Round 10
// baseline (14240.878 us; speedup 1.0000x reference)
//
#include <hip/hip_runtime.h>
#include <stdint.h>

#define B_    32
#define T_    2048
#define D_    512
#define U_    256
#define TSP_  32             // t rows per k_attn workgroup (8 rows/wave)
#define NSL   (T_/TSP_)      // 64 slices per batch

typedef short          bf16x8 __attribute__((ext_vector_type(8)));
typedef unsigned short u16x4  __attribute__((ext_vector_type(4)));
typedef float          f32x4  __attribute__((ext_vector_type(4)));

__device__ __forceinline__ float bf2f(unsigned short u){
  union{unsigned int i; float f;} v; v.i = ((unsigned int)u)<<16; return v.f;
}
__device__ __forceinline__ unsigned short f2bf(float f){
  union{float f; unsigned int i;} v; v.f = f;
  unsigned int r = v.i + 0x7FFFu + ((v.i>>16)&1u);
  return (unsigned short)(r>>16);
}
__device__ __forceinline__ float ftanh(float x){
  float xx = fminf(fmaxf(x,-20.f),20.f);
  float t = __builtin_amdgcn_exp2f(xx * 2.885390082f);   // e^{2x}
  return (t-1.f)*__builtin_amdgcn_rcpf(t+1.f);
}
__device__ __forceinline__ float fexp(float x){
  return __builtin_amdgcn_exp2f(x*1.4426950408889634f);
}

// ---------------- generic fp32 -> bf16 convert (one-time) ------------------
__global__ __launch_bounds__(256) void k_f2b(
    const float* __restrict__ src, unsigned short* __restrict__ dst, int n)
{
  int idx = (blockIdx.x*256 + threadIdx.x)*4;
  int stride = gridDim.x*256*4;
  for (; idx < n; idx += stride){
    float4 v = *(const float4*)(src+idx);
    u16x4 o; o.x=f2bf(v.x); o.y=f2bf(v.y); o.z=f2bf(v.z); o.w=f2bf(v.w);
    *(u16x4*)(dst+idx) = o;
  }
}

// ---------------- P: uxpb = x @ U_a + b_a  (fp32 in, bf16 MFMA) -----------
__global__ __launch_bounds__(256) void k_uxpb(
    const float* __restrict__ x,      // [M=65536][512]
    const float* __restrict__ Ua,     // [512][256]
    const float* __restrict__ ba,     // [256]
    unsigned short* __restrict__ uxpb)// [M][256] bf16
{
  __shared__ unsigned short As[64][40];
  __shared__ unsigned short Bs[64][40];
  int bx = blockIdx.x;
  int nt = bx & 3, mt = bx >> 2;
  int m0 = mt*64, n0 = nt*64;
  int tid = threadIdx.x;
  int lane = tid & 63, w = tid >> 6;
  int wm = w >> 1, wn = w & 1;

  f32x4 acc[2][2] = {};
  int ar = tid >> 2, ak = (tid & 3) * 8;
  int bk = tid >> 3, bn = (tid & 7) * 8;

  for (int k0 = 0; k0 < 512; k0 += 32) {
    const float* ap = x  + (long)(m0+ar)*512 + k0 + ak;
    const float* bp = Ua + (long)(k0+bk)*256 + n0 + bn;
    float4 a0 = *(const float4*)ap, a1 = *(const float4*)(ap+4);
    float4 b0 = *(const float4*)bp, b1 = *(const float4*)(bp+4);
    __syncthreads();
    unsigned short* as = &As[ar][ak];
    as[0]=f2bf(a0.x); as[1]=f2bf(a0.y); as[2]=f2bf(a0.z); as[3]=f2bf(a0.w);
    as[4]=f2bf(a1.x); as[5]=f2bf(a1.y); as[6]=f2bf(a1.z); as[7]=f2bf(a1.w);
    Bs[bn+0][bk]=f2bf(b0.x); Bs[bn+1][bk]=f2bf(b0.y);
    Bs[bn+2][bk]=f2bf(b0.z); Bs[bn+3][bk]=f2bf(b0.w);
    Bs[bn+4][bk]=f2bf(b1.x); Bs[bn+5][bk]=f2bf(b1.y);
    Bs[bn+6][bk]=f2bf(b1.z); Bs[bn+7][bk]=f2bf(b1.w);
    __syncthreads();
    #pragma unroll
    for (int mi = 0; mi < 2; ++mi) {
      bf16x8 a = *(const bf16x8*)&As[wm*32 + mi*16 + (lane&15)][(lane>>4)*8];
      #pragma unroll
      for (int ni = 0; ni < 2; ++ni) {
        bf16x8 b = *(const bf16x8*)&Bs[wn*32 + ni*16 + (lane&15)][(lane>>4)*8];
        acc[mi][ni] = __builtin_amdgcn_mfma_f32_16x16x32_bf16(a, b, acc[mi][ni], 0,0,0);
      }
    }
  }
  #pragma unroll
  for (int mi = 0; mi < 2; ++mi)
  #pragma unroll
  for (int ni = 0; ni < 2; ++ni) {
    int col = n0 + wn*32 + ni*16 + (lane&15);
    float bias = ba[col];
    #pragma unroll
    for (int r = 0; r < 4; ++r) {
      int row = m0 + wm*32 + mi*16 + (lane>>4)*4 + r;
      uxpb[(long)row*256 + col] = f2bf(acc[mi][ni][r] + bias);
    }
  }
}

// ---------------- I0: h0 = tanh(x[:,0] @ W_s), c = 0 -----------------------
__global__ __launch_bounds__(256) void k_init_h(
    const float* __restrict__ x,
    const float* __restrict__ Ws,   // [512][256]
    float* __restrict__ h0,         // [B][256] (buffer 0)
    float* __restrict__ c_ws)
{
  int b = blockIdx.x, tid = threadIdx.x;
  __shared__ float xs[512];
  xs[tid]     = x[(long)b*T_*D_ + tid];
  xs[tid+256] = x[(long)b*T_*D_ + tid + 256];
  __syncthreads();
  float sum = 0.f;
  for (int k = 0; k < 512; ++k) sum = fmaf(xs[k], Ws[(long)k*256 + tid], sum);
  h0[b*256+tid] = ftanh(sum);
  c_ws[b*256+tid] = 0.f;
}

// ---------------- I1: hW partials from h0 ----------------------------------
__global__ __launch_bounds__(256) void k_init_hw(
    const float* __restrict__ Wa,   // [256][256]
    const float* __restrict__ h0,
    float* __restrict__ hW_part)    // [B][8][256]
{
  int wg = blockIdx.x; int b = wg>>3, j = wg&7;
  int tid = threadIdx.x;
  __shared__ float hn[32];
  if (tid < 32) hn[tid] = h0[b*256 + j*32 + tid];
  __syncthreads();
  float sum = 0.f;
  #pragma unroll 8
  for (int w2 = 0; w2 < 32; ++w2) sum = fmaf(hn[w2], Wa[(j*32+w2)*256 + tid], sum);
  hW_part[(b*8+j)*256 + tid] = sum;
}

// energy + weighted-x accumulate for one row pair (all static indices,
// textual macro: no lambdas/arrays-by-pointer -> no scratch)
#define PAIR(U0,U1,X0,X1)                                                     \
{                                                                             \
  float e0, e1, p0_, p1_;                                                     \
  e0  = ftanh(bf2f((unsigned short)(U0.x & 0xFFFFu)) + hw0) * vvx;            \
  e1  = ftanh(bf2f((unsigned short)(U1.x & 0xFFFFu)) + hw0) * vvx;            \
  e0 = fmaf(ftanh(bf2f((unsigned short)(U0.x >> 16)) + hw1), vvy, e0);        \
  e1 = fmaf(ftanh(bf2f((unsigned short)(U1.x >> 16)) + hw1), vvy, e1);        \
  e0 = fmaf(ftanh(bf2f((unsigned short)(U0.y & 0xFFFFu)) + hw2), vvz, e0);    \
  e1 = fmaf(ftanh(bf2f((unsigned short)(U1.y & 0xFFFFu)) + hw2), vvz, e1);    \
  e0 = fmaf(ftanh(bf2f((unsigned short)(U0.y >> 16)) + hw3), vvw, e0);        \
  e1 = fmaf(ftanh(bf2f((unsigned short)(U1.y >> 16)) + hw3), vvw, e1);        \
  e0 += __shfl_xor(e0, 1, 64);   e1 += __shfl_xor(e1, 1, 64);                 \
  e0 += __shfl_xor(e0, 2, 64);   e1 += __shfl_xor(e1, 2, 64);                 \
  e0 += __shfl_xor(e0, 4, 64);   e1 += __shfl_xor(e1, 4, 64);                 \
  e0 += __shfl_xor(e0, 8, 64);   e1 += __shfl_xor(e1, 8, 64);                 \
  e0 += __shfl_xor(e0, 16, 64);  e1 += __shfl_xor(e1, 16, 64);                \
  e0 += __shfl_xor(e0, 32, 64);  e1 += __shfl_xor(e1, 32, 64);                \
  p0_ = fexp(e0); p1_ = fexp(e1);                                             \
  ssum += p0_ + p1_;                                                          \
  acc[0] = fmaf(p1_, bf2f((unsigned short)(X1.x & 0xFFFFu)), fmaf(p0_, bf2f((unsigned short)(X0.x & 0xFFFFu)), acc[0])); \
  acc[1] = fmaf(p1_, bf2f((unsigned short)(X1.x >> 16)),     fmaf(p0_, bf2f((unsigned short)(X0.x >> 16)),     acc[1])); \
  acc[2] = fmaf(p1_, bf2f((unsigned short)(X1.y & 0xFFFFu)), fmaf(p0_, bf2f((unsigned short)(X0.y & 0xFFFFu)), acc[2])); \
  acc[3] = fmaf(p1_, bf2f((unsigned short)(X1.y >> 16)),     fmaf(p0_, bf2f((unsigned short)(X0.y >> 16)),     acc[3])); \
  acc[4] = fmaf(p1_, bf2f((unsigned short)(X1.z & 0xFFFFu)), fmaf(p0_, bf2f((unsigned short)(X0.z & 0xFFFFu)), acc[4])); \
  acc[5] = fmaf(p1_, bf2f((unsigned short)(X1.z >> 16)),     fmaf(p0_, bf2f((unsigned short)(X0.z >> 16)),     acc[5])); \
  acc[6] = fmaf(p1_, bf2f((unsigned short)(X1.w & 0xFFFFu)), fmaf(p0_, bf2f((unsigned short)(X0.w & 0xFFFFu)), acc[6])); \
  acc[7] = fmaf(p1_, bf2f((unsigned short)(X1.w >> 16)),     fmaf(p0_, bf2f((unsigned short)(X0.w >> 16)),     acc[7])); \
}

// ---------------- S1: energies + exp (max=0 safe) + ctx partials -----------
// grid 2048 = 8 WGs/CU resident; VGPR must stay <=64 for 8 waves/SIMD.
template<int XBF>
__global__ __launch_bounds__(256, 8) void k_attn(
    const float* __restrict__ xf,              // [B][T][512] fp32
    const unsigned short* __restrict__ xb,     // [B][T][512] bf16
    const unsigned short* __restrict__ uxpb,   // [B][T][256] bf16
    const float* __restrict__ Va,              // [256]
    const float* __restrict__ hW_part,         // [B][8][256]
    float* __restrict__ part_s,                // [B][NSL]
    float* __restrict__ part_ctx)              // [B][NSL][512]
{
  int wg = blockIdx.x;
  int b = wg >> 6, sl = wg & 63;
  int tid = threadIdx.x, lane = tid & 63, w = tid >> 6;

  __shared__ float hws[256];
  __shared__ float wsum[4];
  __shared__ float wctx[4][512];

  // wave w owns rows sl*32 + w*8 + {0..7}
  const long rbase = (long)b*T_ + sl*TSP_ + w*8;
  const unsigned short* up0 = uxpb + rbase*256 + lane*4;
  const unsigned short* xp0 = xb   + rbase*512 + lane*8;

  // issue all 8 uxpb row loads + first x pair up front; they complete
  // during the hws staging barrier (free overlap).
  uint2 u0, u1, u2, u3, u4, u5, u6, u7;
  uint4 xq0, xq1;
  if (XBF) {
    u0 = *(const uint2*)(up0);
    u1 = *(const uint2*)(up0 + 256);
    u2 = *(const uint2*)(up0 + 512);
    u3 = *(const uint2*)(up0 + 768);
    u4 = *(const uint2*)(up0 + 1024);
    u5 = *(const uint2*)(up0 + 1280);
    u6 = *(const uint2*)(up0 + 1536);
    u7 = *(const uint2*)(up0 + 1792);
    xq0 = *(const uint4*)(xp0);
    xq1 = *(const uint4*)(xp0 + 512);
  }

  {
    float hsum = 0.f;
    #pragma unroll
    for (int j = 0; j < 8; ++j) hsum += hW_part[(b*8+j)*256 + tid];
    hws[tid] = hsum;
  }
  __syncthreads();
  float hw0 = hws[lane*4+0], hw1 = hws[lane*4+1];
  float hw2 = hws[lane*4+2], hw3 = hws[lane*4+3];
  float4 vv = *(const float4*)(Va + lane*4);
  float vvx = vv.x, vvy = vv.y, vvz = vv.z, vvw = vv.w;

  float ssum = 0.f;
  float acc[8] = {0,0,0,0,0,0,0,0};

  if (XBF) {
    uint4 nq0 = *(const uint4*)(xp0 + 1024);
    uint4 nq1 = *(const uint4*)(xp0 + 1536);
    PAIR(u0, u1, xq0, xq1);
    xq0 = *(const uint4*)(xp0 + 2048);
    xq1 = *(const uint4*)(xp0 + 2560);
    PAIR(u2, u3, nq0, nq1);
    nq0 = *(const uint4*)(xp0 + 3072);
    nq1 = *(const uint4*)(xp0 + 3584);
    PAIR(u4, u5, xq0, xq1);
    PAIR(u6, u7, nq0, nq1);
  } else {
    const float* pf0 = xf + rbase*512 + lane*8;
    for (int i = 0; i < 8; i += 2) {
      uint2 a0 = *(const uint2*)(up0 + (long)i*256);
      uint2 a1 = *(const uint2*)(up0 + (long)(i+1)*256);
      float e0 = 0.f, e1 = 0.f;
      e0 = fmaf(ftanh(bf2f((unsigned short)(a0.x & 0xFFFF)) + hw0), vvx, e0);
      e1 = fmaf(ftanh(bf2f((unsigned short)(a1.x & 0xFFFF)) + hw0), vvx, e1);
      e0 = fmaf(ftanh(bf2f((unsigned short)(a0.x >> 16))    + hw1), vvy, e0);
      e1 = fmaf(ftanh(bf2f((unsigned short)(a1.x >> 16))    + hw1), vvy, e1);
      e0 = fmaf(ftanh(bf2f((unsigned short)(a0.y & 0xFFFF)) + hw2), vvz, e0);
      e1 = fmaf(ftanh(bf2f((unsigned short)(a1.y & 0xFFFF)) + hw2), vvz, e1);
      e0 = fmaf(ftanh(bf2f((unsigned short)(a0.y >> 16))    + hw3), vvw, e0);
      e1 = fmaf(ftanh(bf2f((unsigned short)(a1.y >> 16))    + hw3), vvw, e1);
      #pragma unroll
      for (int o = 1; o < 64; o <<= 1) {
        e0 += __shfl_xor(e0, o, 64);
        e1 += __shfl_xor(e1, o, 64);
      }
      float p0 = fexp(e0), p1 = fexp(e1);
      ssum += p0 + p1;
      const float* p0p = pf0 + (long)i*512;
      const float* p1p = pf0 + (long)(i+1)*512;
      float4 v00 = *(const float4*)p0p, v01 = *(const float4*)(p0p+4);
      float4 v10 = *(const float4*)p1p, v11 = *(const float4*)(p1p+4);
      float x0a[8] = {v00.x,v00.y,v00.z,v00.w,v01.x,v01.y,v01.z,v01.w};
      float x1a[8] = {v10.x,v10.y,v10.z,v10.w,v11.x,v11.y,v11.z,v11.w};
      #pragma unroll
      for (int j = 0; j < 8; ++j)
        acc[j] = fmaf(p1, x1a[j], fmaf(p0, x0a[j], acc[j]));
    }
  }

  if (lane == 0) wsum[w] = ssum;
  #pragma unroll
  for (int j = 0; j < 8; ++j) wctx[w][lane*8+j] = acc[j];
  __syncthreads();
  #pragma unroll
  for (int d = tid; d < 512; d += 256)
    part_ctx[(long)(b*NSL+sl)*512 + d] =
      wctx[0][d] + wctx[1][d] + wctx[2][d] + wctx[3][d];
  if (tid == 0)
    part_s[b*NSL+sl] = wsum[0] + wsum[1] + wsum[2] + wsum[3];
}

// ---------------- S2: combine + gates + h/c + next hW (8 WGs/batch) --------
template<int WBF>
__global__ __launch_bounds__(256) void k_step(
    const float* __restrict__ Wk,            // [512][1024] fp32
    const float* __restrict__ Wr,            // [256][1024] fp32
    const unsigned short* __restrict__ Wkb,  // bf16 copies (if WBF)
    const unsigned short* __restrict__ Wrb,
    const float* __restrict__ bias,          // [1024]
    const float* __restrict__ Wa,            // [256][256] fp32
    const unsigned short* __restrict__ Wab,
    const float* __restrict__ part_s,
    const float* __restrict__ part_ctx,
    const float* __restrict__ h_in,          // [B][256]
    float* __restrict__ h_out,               // [B][256]
    float* __restrict__ c_ws,                // [B][256]
    float* __restrict__ hW_part,             // [B][8][256]
    float* __restrict__ out,                 // [B][TDEC][256] fp32
    int step, int TDEC)
{
  int wg = blockIdx.x;
  int b = wg >> 3, j = wg & 7;
  int tid = threadIdx.x;

  __shared__ float ctx[512];
  __shared__ float hsh[256];
  __shared__ float zp[2][128];
  __shared__ float hn[32];

  float S = 0.f;
  #pragma unroll 8
  for (int i = 0; i < NSL; ++i) S += part_s[b*NSL+i];
  float invS = 1.f / S;

  hsh[tid] = h_in[b*256 + tid];
  #pragma unroll
  for (int d = tid; d < 512; d += 256) {
    float c = 0.f;
    #pragma unroll 8
    for (int i = 0; i < NSL; ++i)
      c += part_ctx[(long)(b*NSL+i)*512 + d];
    ctx[d] = c * invS;
  }
  __syncthreads();

  // z GEMV: 128 cols (4 gates x 32 u) split across 2 K-halves
  int c_  = tid & 127, half = tid >> 7;
  int g   = c_ >> 5;
  int col = g*256 + j*32 + (c_ & 31);
  float z = 0.f;
  if (WBF) {
    if (half == 0) {
      for (int k = 0; k < 384; ++k) z = fmaf(ctx[k], bf2f(Wkb[(long)k*1024 + col]), z);
    } else {
      for (int k = 384; k < 512; ++k) z = fmaf(ctx[k], bf2f(Wkb[(long)k*1024 + col]), z);
      for (int k = 0; k < 256; ++k)   z = fmaf(hsh[k], bf2f(Wrb[(long)k*1024 + col]), z);
    }
  } else {
    if (half == 0) {
      for (int k = 0; k < 384; ++k) z = fmaf(ctx[k], Wk[(long)k*1024 + col], z);
    } else {
      for (int k = 384; k < 512; ++k) z = fmaf(ctx[k], Wk[(long)k*1024 + col], z);
      for (int k = 0; k < 256; ++k)   z = fmaf(hsh[k], Wr[(long)k*1024 + col], z);
    }
  }
  zp[half][c_] = z;
  __syncthreads();
  if (tid < 128) zp[0][tid] = zp[0][tid] + zp[1][tid] + bias[col];
  __syncthreads();

  if (tid < 32) {
    float zi = zp[0][tid], zf = zp[0][32+tid], zc = zp[0][64+tid], zo = zp[0][96+tid];
    float ig = fminf(fmaxf(0.2f*zi+0.5f, 0.f), 1.f);
    float fg = fminf(fmaxf(0.2f*zf+0.5f, 0.f), 1.f);
    float og = fminf(fmaxf(0.2f*zo+0.5f, 0.f), 1.f);
    int u = j*32 + tid;
    float c_old = c_ws[b*256+u];
    float c_new = fg*c_old + ig*ftanh(zc);
    float h_new = og*ftanh(c_new);
    c_ws[b*256+u]  = c_new;
    h_out[b*256+u] = h_new;
    out[((long)b*TDEC + step)*256 + u] = h_new;
    hn[tid] = h_new;
  }
  __syncthreads();

  {
    float sum = 0.f;
    if (WBF) {
      #pragma unroll 8
      for (int w2 = 0; w2 < 32; ++w2)
        sum = fmaf(hn[w2], bf2f(Wab[(j*32+w2)*256 + tid]), sum);
    } else {
      #pragma unroll 8
      for (int w2 = 0; w2 < 32; ++w2)
        sum = fmaf(hn[w2], Wa[(j*32+w2)*256 + tid], sum);
    }
    hW_part[(b*8+j)*256 + tid] = sum;
  }
}

// ---------------------------------------------------------------------------
extern "C" void kernel_launch(void* const* d_in, const int* in_sizes, int n_in,
                              void* d_out, int out_size, void* d_ws, size_t ws_size,
                              hipStream_t stream)
{
  const float* x  = (const float*)d_in[0];
  const float* Ws = (const float*)d_in[1];
  const float* Ua = (const float*)d_in[2];
  const float* ba = (const float*)d_in[3];
  const float* Wa = (const float*)d_in[4];
  const float* Va = (const float*)d_in[5];
  const float* Wk = (const float*)d_in[6];
  const float* Wr = (const float*)d_in[7];
  const float* bs = (const float*)d_in[8];
  int TDEC = out_size / (B_ * U_);

  size_t off = 0;
  char* base = (char*)d_ws;
  unsigned short* uxpb = (unsigned short*)(base+off); off += (size_t)B_*T_*U_*2;
  float* part_ctx = (float*)(base+off);               off += (size_t)B_*NSL*512*4;
  float* part_s   = (float*)(base+off);               off += (size_t)B_*NSL*4;
  float* hW_part  = (float*)(base+off);               off += (size_t)B_*8*U_*4;
  float* h_buf    = (float*)(base+off);               off += (size_t)2*B_*U_*4;
  float* c_ws     = (float*)(base+off);               off += (size_t)B_*U_*4;
  unsigned short* x_bf = (unsigned short*)(base+off); off += (size_t)B_*T_*D_*2;
  bool use_xbf = (off <= ws_size);
  unsigned short* wk_bf = (unsigned short*)(base+off); off += (size_t)D_*4*U_*2;
  unsigned short* wr_bf = (unsigned short*)(base+off); off += (size_t)U_*4*U_*2;
  unsigned short* wa_bf = (unsigned short*)(base+off); off += (size_t)U_*U_*2;
  bool use_wbf = (off <= ws_size);

  k_uxpb  <<<(B_*T_/64)*(U_/64), 256, 0, stream>>>(x, Ua, ba, uxpb);
  if (use_xbf) k_f2b<<<2048, 256, 0, stream>>>(x, x_bf, B_*T_*D_);
  if (use_wbf) {
    k_f2b<<<512, 256, 0, stream>>>(Wk, wk_bf, D_*4*U_);
    k_f2b<<<256, 256, 0, stream>>>(Wr, wr_bf, U_*4*U_);
    k_f2b<<<64,  256, 0, stream>>>(Wa, wa_bf, U_*U_);
  }
  k_init_h<<<B_,  256, 0, stream>>>(x, Ws, h_buf, c_ws);
  k_init_hw<<<B_*8, 256, 0, stream>>>(Wa, h_buf, hW_part);

  for (int s = 0; s < TDEC; ++s) {
    float* h_in  = h_buf + (s & 1)     * B_ * U_;
    float* h_out = h_buf + ((s+1) & 1) * B_ * U_;
    if (use_xbf)
      k_attn<1><<<B_*NSL, 256, 0, stream>>>(x, x_bf, uxpb, Va, hW_part,
                                            part_s, part_ctx);
    else
      k_attn<0><<<B_*NSL, 256, 0, stream>>>(x, x_bf, uxpb, Va, hW_part,
                                            part_s, part_ctx);
    if (use_wbf)
      k_step<1><<<B_*8, 256, 0, stream>>>(Wk, Wr, wk_bf, wr_bf, bs, Wa, wa_bf,
                                          part_s, part_ctx, h_in, h_out,
                                          c_ws, hW_part, (float*)d_out, s, TDEC);
    else
      k_step<0><<<B_*8, 256, 0, stream>>>(Wk, Wr, wk_bf, wr_bf, bs, Wa, wa_bf,
                                          part_s, part_ctx, h_in, h_out,
                                          c_ws, hW_part, (float*)d_out, s, TDEC);
  }
}

// Round 11
// 9410.339 us; speedup vs baseline: 1.5133x; 1.5133x over previous
//
#include <hip/hip_runtime.h>
#include <stdint.h>

#define B_    32
#define T_    2048
#define D_    512
#define U_    256
#define TSP_  64             // t rows per k_attn workgroup
#define NSL   (T_/TSP_)      // 32 slices per batch

typedef short          bf16x8 __attribute__((ext_vector_type(8)));
typedef unsigned short u16x4  __attribute__((ext_vector_type(4)));
typedef float          f32x4  __attribute__((ext_vector_type(4)));
typedef float          f32x2  __attribute__((ext_vector_type(2)));

__device__ __forceinline__ float bf2f(unsigned short u){
  union{unsigned int i; float f;} v; v.i = ((unsigned int)u)<<16; return v.f;
}
__device__ __forceinline__ unsigned short f2bf(float f){
  union{float f; unsigned int i;} v; v.f = f;
  unsigned int r = v.i + 0x7FFFu + ((v.i>>16)&1u);
  return (unsigned short)(r>>16);
}
__device__ __forceinline__ float ftanh(float x){
  float xx = fminf(fmaxf(x,-20.f),20.f);
  float t = __builtin_amdgcn_exp2f(xx * 2.885390082f);   // e^{2x}
  return (t-1.f)*__builtin_amdgcn_rcpf(t+1.f);
}
__device__ __forceinline__ float fexp(float x){
  return __builtin_amdgcn_exp2f(x*1.4426950408889634f);
}

// ---- fp8 e4m3fn: manual RNE encode (one-time), fast decode (hot loop) -----
__device__ unsigned int f2e4m3_1(float f){
  union{float f; unsigned int i;} v; v.f = f;
  unsigned int s = (v.i>>31)<<7;
  float af = fabsf(f);
  af = fminf(af, 448.f);
  unsigned int code;
  if (af < 0.015625f){                       // denormal (incl. 0)
    code = (unsigned int)rintf(af*512.f);    // 0..8 (8 == e=1,m=0: still valid)
  } else {
    int ex; float mant = frexpf(af,&ex);     // af = mant*2^ex, mant in [0.5,1)
    int E = ex-1;
    int m = (int)rintf(mant*16.f - 8.f);     // 0..8
    if (m==8){ E+=1; m=0; }
    if (E>8){ E=8; m=6; }                    // clamp to 448
    code = ((unsigned int)(E+7)<<3) | (unsigned int)m;
  }
  return s|code;
}

__device__ __forceinline__ float e4m3f(unsigned int b){
  int e = (int)((b>>3)&15u), m = (int)(b&7u);
  int M = e ? (m+8) : m;
  M = (b&128u) ? -M : M;
  int E = (e ? e : 1) - 10;
  return ldexpf((float)M, E);
}

#if __has_builtin(__builtin_amdgcn_cvt_pk_f32_fp8)
#define DEC8(Q,F) {                                                      \
  f32x2 t_;                                                              \
  t_ = __builtin_amdgcn_cvt_pk_f32_fp8((int)Q.x, false); F[0]=t_[0]; F[1]=t_[1]; \
  t_ = __builtin_amdgcn_cvt_pk_f32_fp8((int)Q.x, true ); F[2]=t_[0]; F[3]=t_[1]; \
  t_ = __builtin_amdgcn_cvt_pk_f32_fp8((int)Q.y, false); F[4]=t_[0]; F[5]=t_[1]; \
  t_ = __builtin_amdgcn_cvt_pk_f32_fp8((int)Q.y, true ); F[6]=t_[0]; F[7]=t_[1]; }
#else
#define DEC8(Q,F) {                                                      \
  F[0]=e4m3f(Q.x&255u);      F[1]=e4m3f((Q.x>>8)&255u);                  \
  F[2]=e4m3f((Q.x>>16)&255u);F[3]=e4m3f(Q.x>>24);                        \
  F[4]=e4m3f(Q.y&255u);      F[5]=e4m3f((Q.y>>8)&255u);                  \
  F[6]=e4m3f((Q.y>>16)&255u);F[7]=e4m3f(Q.y>>24); }
#endif

// ---------------- one-time converts ---------------------------------------
__global__ __launch_bounds__(256) void k_f2b(
    const float* __restrict__ src, unsigned short* __restrict__ dst, int n)
{
  int idx = (blockIdx.x*256 + threadIdx.x)*4;
  int stride = gridDim.x*256*4;
  for (; idx < n; idx += stride){
    float4 v = *(const float4*)(src+idx);
    u16x4 o; o.x=f2bf(v.x); o.y=f2bf(v.y); o.z=f2bf(v.z); o.w=f2bf(v.w);
    *(u16x4*)(dst+idx) = o;
  }
}

__global__ __launch_bounds__(256) void k_f2e8(
    const float* __restrict__ src, unsigned char* __restrict__ dst, int n)
{
  int idx = (blockIdx.x*256 + threadIdx.x)*8;
  int stride = gridDim.x*256*8;
  for (; idx < n; idx += stride){
    float4 a = *(const float4*)(src+idx);
    float4 b = *(const float4*)(src+idx+4);
    unsigned int w0 = f2e4m3_1(a.x) | (f2e4m3_1(a.y)<<8) |
                      (f2e4m3_1(a.z)<<16) | (f2e4m3_1(a.w)<<24);
    unsigned int w1 = f2e4m3_1(b.x) | (f2e4m3_1(b.y)<<8) |
                      (f2e4m3_1(b.z)<<16) | (f2e4m3_1(b.w)<<24);
    uint2 o; o.x = w0; o.y = w1;
    *(uint2*)(dst+idx) = o;
  }
}

// ---------------- P: uxpb = x @ U_a + b_a  (fp32 in, bf16 MFMA) -----------
__global__ __launch_bounds__(256) void k_uxpb(
    const float* __restrict__ x,      // [M=65536][512]
    const float* __restrict__ Ua,     // [512][256]
    const float* __restrict__ ba,     // [256]
    unsigned short* __restrict__ uxpb)// [M][256] bf16
{
  __shared__ unsigned short As[64][40];
  __shared__ unsigned short Bs[64][40];
  int bx = blockIdx.x;
  int nt = bx & 3, mt = bx >> 2;
  int m0 = mt*64, n0 = nt*64;
  int tid = threadIdx.x;
  int lane = tid & 63, w = tid >> 6;
  int wm = w >> 1, wn = w & 1;

  f32x4 acc[2][2] = {};
  int ar = tid >> 2, ak = (tid & 3) * 8;
  int bk = tid >> 3, bn = (tid & 7) * 8;

  for (int k0 = 0; k0 < 512; k0 += 32) {
    const float* ap = x  + (long)(m0+ar)*512 + k0 + ak;
    const float* bp = Ua + (long)(k0+bk)*256 + n0 + bn;
    float4 a0 = *(const float4*)ap, a1 = *(const float4*)(ap+4);
    float4 b0 = *(const float4*)bp, b1 = *(const float4*)(bp+4);
    __syncthreads();
    unsigned short* as = &As[ar][ak];
    as[0]=f2bf(a0.x); as[1]=f2bf(a0.y); as[2]=f2bf(a0.z); as[3]=f2bf(a0.w);
    as[4]=f2bf(a1.x); as[5]=f2bf(a1.y); as[6]=f2bf(a1.z); as[7]=f2bf(a1.w);
    Bs[bn+0][bk]=f2bf(b0.x); Bs[bn+1][bk]=f2bf(b0.y);
    Bs[bn+2][bk]=f2bf(b0.z); Bs[bn+3][bk]=f2bf(b0.w);
    Bs[bn+4][bk]=f2bf(b1.x); Bs[bn+5][bk]=f2bf(b1.y);
    Bs[bn+6][bk]=f2bf(b1.z); Bs[bn+7][bk]=f2bf(b1.w);
    __syncthreads();
    #pragma unroll
    for (int mi = 0; mi < 2; ++mi) {
      bf16x8 a = *(const bf16x8*)&As[wm*32 + mi*16 + (lane&15)][(lane>>4)*8];
      #pragma unroll
      for (int ni = 0; ni < 2; ++ni) {
        bf16x8 b = *(const bf16x8*)&Bs[wn*32 + ni*16 + (lane&15)][(lane>>4)*8];
        acc[mi][ni] = __builtin_amdgcn_mfma_f32_16x16x32_bf16(a, b, acc[mi][ni], 0,0,0);
      }
    }
  }
  #pragma unroll
  for (int mi = 0; mi < 2; ++mi)
  #pragma unroll
  for (int ni = 0; ni < 2; ++ni) {
    int col = n0 + wn*32 + ni*16 + (lane&15);
    float bias = ba[col];
    #pragma unroll
    for (int r = 0; r < 4; ++r) {
      int row = m0 + wm*32 + mi*16 + (lane>>4)*4 + r;
      uxpb[(long)row*256 + col] = f2bf(acc[mi][ni][r] + bias);
    }
  }
}

// ---------------- I0: h0 = tanh(x[:,0] @ W_s), c = 0 -----------------------
__global__ __launch_bounds__(256) void k_init_h(
    const float* __restrict__ x,
    const float* __restrict__ Ws,   // [512][256]
    float* __restrict__ h0,         // [B][256] (buffer 0)
    float* __restrict__ c_ws)
{
  int b = blockIdx.x, tid = threadIdx.x;
  __shared__ float xs[512];
  xs[tid]     = x[(long)b*T_*D_ + tid];
  xs[tid+256] = x[(long)b*T_*D_ + tid + 256];
  __syncthreads();
  float sum = 0.f;
  for (int k = 0; k < 512; ++k) sum = fmaf(xs[k], Ws[(long)k*256 + tid], sum);
  h0[b*256+tid] = ftanh(sum);
  c_ws[b*256+tid] = 0.f;
}

// ---------------- I1: hW partials from h0 ----------------------------------
__global__ __launch_bounds__(256) void k_init_hw(
    const float* __restrict__ Wa,   // [256][256]
    const float* __restrict__ h0,
    float* __restrict__ hW_part)    // [B][8][256]
{
  int wg = blockIdx.x; int b = wg>>3, j = wg&7;
  int tid = threadIdx.x;
  __shared__ float hn[32];
  if (tid < 32) hn[tid] = h0[b*256 + j*32 + tid];
  __syncthreads();
  float sum = 0.f;
  #pragma unroll 8
  for (int w2 = 0; w2 < 32; ++w2) sum = fmaf(hn[w2], Wa[(j*32+w2)*256 + tid], sum);
  hW_part[(b*8+j)*256 + tid] = sum;
}

// ---------------- S1: energies + exp (max=0 safe) + ctx partials -----------
// XBF=1: x from fp8 e4m3 (32MB) ; XBF=0: x from fp32 (fallback)
template<int XBF>
__global__ __launch_bounds__(256) void k_attn(
    const float* __restrict__ xf,              // [B][T][512] fp32
    const unsigned char* __restrict__ x8,      // [B][T][512] fp8
    const unsigned short* __restrict__ uxpb,   // [B][T][256] bf16
    const float* __restrict__ Va,              // [256]
    const float* __restrict__ hW_part,         // [B][8][256]
    float* __restrict__ part_s,                // [B][NSL]
    float* __restrict__ part_ctx)              // [B][NSL][512]
{
  int wg = blockIdx.x;
  int b = wg >> 5, sl = wg & 31;
  int tid = threadIdx.x, lane = tid & 63, w = tid >> 6;

  __shared__ float hws[256];
  __shared__ float wsum[4];
  __shared__ float wctx[4][512];

  {
    float hsum = 0.f;
    #pragma unroll
    for (int j = 0; j < 8; ++j) hsum += hW_part[(b*8+j)*256 + tid];
    hws[tid] = hsum;
  }
  __syncthreads();
  float hw0 = hws[lane*4+0], hw1 = hws[lane*4+1];
  float hw2 = hws[lane*4+2], hw3 = hws[lane*4+3];
  float4 vv = *(const float4*)(Va + lane*4);

  // wave w owns rows t0 + w*16 + {0..15}
  const long rbase = (long)b*T_ + sl*TSP_ + w*16;
  const unsigned short* up0 = uxpb + rbase*256 + lane*4;
  const unsigned char*  xp8 = x8   + rbase*512 + lane*8;
  const float*          pf0 = xf   + rbase*512 + lane*8;

  float ssum = 0.f;
  float acc[8] = {0,0,0,0,0,0,0,0};

  #pragma unroll
  for (int i = 0; i < 16; i += 2) {
    uint2 u0 = *(const uint2*)(up0 + (long)i*256);
    uint2 u1 = *(const uint2*)(up0 + (long)(i+1)*256);
    float e0 = 0.f, e1 = 0.f;
    e0 = fmaf(ftanh(bf2f((unsigned short)(u0.x & 0xFFFF)) + hw0), vv.x, e0);
    e1 = fmaf(ftanh(bf2f((unsigned short)(u1.x & 0xFFFF)) + hw0), vv.x, e1);
    e0 = fmaf(ftanh(bf2f((unsigned short)(u0.x >> 16))    + hw1), vv.y, e0);
    e1 = fmaf(ftanh(bf2f((unsigned short)(u1.x >> 16))    + hw1), vv.y, e1);
    e0 = fmaf(ftanh(bf2f((unsigned short)(u0.y & 0xFFFF)) + hw2), vv.z, e0);
    e1 = fmaf(ftanh(bf2f((unsigned short)(u1.y & 0xFFFF)) + hw2), vv.z, e1);
    e0 = fmaf(ftanh(bf2f((unsigned short)(u0.y >> 16))    + hw3), vv.w, e0);
    e1 = fmaf(ftanh(bf2f((unsigned short)(u1.y >> 16))    + hw3), vv.w, e1);
    #pragma unroll
    for (int o = 1; o < 64; o <<= 1) {
      e0 += __shfl_xor(e0, o, 64);
      e1 += __shfl_xor(e1, o, 64);
    }
    float p0 = fexp(e0), p1 = fexp(e1);   // |e| <= sum|Va| ~10: un-maxed safe
    ssum += p0 + p1;
    if (XBF) {
      uint2 q0 = *(const uint2*)(xp8 + (long)i*512);
      uint2 q1 = *(const uint2*)(xp8 + (long)(i+1)*512);
      float x0a[8], x1a[8];
      DEC8(q0, x0a);
      DEC8(q1, x1a);
      #pragma unroll
      for (int j = 0; j < 8; ++j)
        acc[j] = fmaf(p1, x1a[j], fmaf(p0, x0a[j], acc[j]));
    } else {
      const float* p0p = pf0 + (long)i*512;
      const float* p1p = pf0 + (long)(i+1)*512;
      float4 v00 = *(const float4*)p0p, v01 = *(const float4*)(p0p+4);
      float4 v10 = *(const float4*)p1p, v11 = *(const float4*)(p1p+4);
      float x0a[8] = {v00.x,v00.y,v00.z,v00.w,v01.x,v01.y,v01.z,v01.w};
      float x1a[8] = {v10.x,v10.y,v10.z,v10.w,v11.x,v11.y,v11.z,v11.w};
      #pragma unroll
      for (int j = 0; j < 8; ++j)
        acc[j] = fmaf(p1, x1a[j], fmaf(p0, x0a[j], acc[j]));
    }
  }

  if (lane == 0) wsum[w] = ssum;
  #pragma unroll
  for (int j = 0; j < 8; ++j) wctx[w][lane*8+j] = acc[j];
  __syncthreads();
  #pragma unroll
  for (int d = tid; d < 512; d += 256)
    part_ctx[(long)(b*NSL+sl)*512 + d] =
      wctx[0][d] + wctx[1][d] + wctx[2][d] + wctx[3][d];
  if (tid == 0)
    part_s[b*NSL+sl] = wsum[0] + wsum[1] + wsum[2] + wsum[3];
}

// ---------------- S2: combine + gates + h/c + next hW (8 WGs/batch) --------
template<int WBF>
__global__ __launch_bounds__(256) void k_step(
    const float* __restrict__ Wk,            // [512][1024] fp32
    const float* __restrict__ Wr,            // [256][1024] fp32
    const unsigned short* __restrict__ Wkb,  // bf16 copies (if WBF)
    const unsigned short* __restrict__ Wrb,
    const float* __restrict__ bias,          // [1024]
    const float* __restrict__ Wa,            // [256][256] fp32
    const unsigned short* __restrict__ Wab,
    const float* __restrict__ part_s,
    const float* __restrict__ part_ctx,
    const float* __restrict__ h_in,          // [B][256]
    float* __restrict__ h_out,               // [B][256]
    float* __restrict__ c_ws,                // [B][256]
    float* __restrict__ hW_part,             // [B][8][256]
    float* __restrict__ out,                 // [B][TDEC][256] fp32
    int step, int TDEC)
{
  int wg = blockIdx.x;
  int b = wg >> 3, j = wg & 7;
  int tid = threadIdx.x;

  __shared__ float ctx[512];
  __shared__ float hsh[256];
  __shared__ float zp[2][128];
  __shared__ float hn[32];

  float S = 0.f;
  #pragma unroll 8
  for (int i = 0; i < NSL; ++i) S += part_s[b*NSL+i];
  float invS = 1.f / S;

  hsh[tid] = h_in[b*256 + tid];
  #pragma unroll
  for (int d = tid; d < 512; d += 256) {
    float c = 0.f;
    #pragma unroll 8
    for (int i = 0; i < NSL; ++i)
      c += part_ctx[(long)(b*NSL+i)*512 + d];
    ctx[d] = c * invS;
  }
  __syncthreads();

  // z GEMV: 128 cols (4 gates x 32 u) split across 2 K-halves
  int c_  = tid & 127, half = tid >> 7;
  int g   = c_ >> 5;
  int col = g*256 + j*32 + (c_ & 31);
  float z = 0.f;
  if (WBF) {
    if (half == 0) {
      for (int k = 0; k < 384; ++k) z = fmaf(ctx[k], bf2f(Wkb[(long)k*1024 + col]), z);
    } else {
      for (int k = 384; k < 512; ++k) z = fmaf(ctx[k], bf2f(Wkb[(long)k*1024 + col]), z);
      for (int k = 0; k < 256; ++k)   z = fmaf(hsh[k], bf2f(Wrb[(long)k*1024 + col]), z);
    }
  } else {
    if (half == 0) {
      for (int k = 0; k < 384; ++k) z = fmaf(ctx[k], Wk[(long)k*1024 + col], z);
    } else {
      for (int k = 384; k < 512; ++k) z = fmaf(ctx[k], Wk[(long)k*1024 + col], z);
      for (int k = 0; k < 256; ++k)   z = fmaf(hsh[k], Wr[(long)k*1024 + col], z);
    }
  }
  zp[half][c_] = z;
  __syncthreads();
  if (tid < 128) zp[0][tid] = zp[0][tid] + zp[1][tid] + bias[col];
  __syncthreads();

  if (tid < 32) {
    float zi = zp[0][tid], zf = zp[0][32+tid], zc = zp[0][64+tid], zo = zp[0][96+tid];
    float ig = fminf(fmaxf(0.2f*zi+0.5f, 0.f), 1.f);
    float fg = fminf(fmaxf(0.2f*zf+0.5f, 0.f), 1.f);
    float og = fminf(fmaxf(0.2f*zo+0.5f, 0.f), 1.f);
    int u = j*32 + tid;
    float c_old = c_ws[b*256+u];
    float c_new = fg*c_old + ig*ftanh(zc);
    float h_new = og*ftanh(c_new);
    c_ws[b*256+u]  = c_new;
    h_out[b*256+u] = h_new;
    out[((long)b*TDEC + step)*256 + u] = h_new;
    hn[tid] = h_new;
  }
  __syncthreads();

  {
    float sum = 0.f;
    if (WBF) {
      #pragma unroll 8
      for (int w2 = 0; w2 < 32; ++w2)
        sum = fmaf(hn[w2], bf2f(Wab[(j*32+w2)*256 + tid]), sum);
    } else {
      #pragma unroll 8
      for (int w2 = 0; w2 < 32; ++w2)
        sum = fmaf(hn[w2], Wa[(j*32+w2)*256 + tid], sum);
    }
    hW_part[(b*8+j)*256 + tid] = sum;
  }
}

// ---------------------------------------------------------------------------
extern "C" void kernel_launch(void* const* d_in, const int* in_sizes, int n_in,
                              void* d_out, int out_size, void* d_ws, size_t ws_size,
                              hipStream_t stream)
{
  const float* x  = (const float*)d_in[0];
  const float* Ws = (const float*)d_in[1];
  const float* Ua = (const float*)d_in[2];
  const float* ba = (const float*)d_in[3];
  const float* Wa = (const float*)d_in[4];
  const float* Va = (const float*)d_in[5];
  const float* Wk = (const float*)d_in[6];
  const float* Wr = (const float*)d_in[7];
  const float* bs = (const float*)d_in[8];
  int TDEC = out_size / (B_ * U_);

  size_t off = 0;
  char* base = (char*)d_ws;
  unsigned short* uxpb = (unsigned short*)(base+off); off += (size_t)B_*T_*U_*2;
  float* part_ctx = (float*)(base+off);               off += (size_t)B_*NSL*512*4;
  float* part_s   = (float*)(base+off);               off += (size_t)B_*NSL*4;
  float* hW_part  = (float*)(base+off);               off += (size_t)B_*8*U_*4;
  float* h_buf    = (float*)(base+off);               off += (size_t)2*B_*U_*4;
  float* c_ws     = (float*)(base+off);               off += (size_t)B_*U_*4;
  unsigned char* x_f8 = (unsigned char*)(base+off);   off += (size_t)B_*T_*D_;
  bool use_x8 = (off <= ws_size);
  unsigned short* wk_bf = (unsigned short*)(base+off); off += (size_t)D_*4*U_*2;
  unsigned short* wr_bf = (unsigned short*)(base+off); off += (size_t)U_*4*U_*2;
  unsigned short* wa_bf = (unsigned short*)(base+off); off += (size_t)U_*U_*2;
  bool use_wbf = (off <= ws_size);

  k_uxpb  <<<(B_*T_/64)*(U_/64), 256, 0, stream>>>(x, Ua, ba, uxpb);
  if (use_x8) k_f2e8<<<2048, 256, 0, stream>>>(x, x_f8, B_*T_*D_);
  if (use_wbf) {
    k_f2b<<<512, 256, 0, stream>>>(Wk, wk_bf, D_*4*U_);
    k_f2b<<<256, 256, 0, stream>>>(Wr, wr_bf, U_*4*U_);
    k_f2b<<<64,  256, 0, stream>>>(Wa, wa_bf, U_*U_);
  }
  k_init_h<<<B_,  256, 0, stream>>>(x, Ws, h_buf, c_ws);
  k_init_hw<<<B_*8, 256, 0, stream>>>(Wa, h_buf, hW_part);

  for (int s = 0; s < TDEC; ++s) {
    float* h_in  = h_buf + (s & 1)     * B_ * U_;
    float* h_out = h_buf + ((s+1) & 1) * B_ * U_;
    if (use_x8)
      k_attn<1><<<B_*NSL, 256, 0, stream>>>(x, x_f8, uxpb, Va, hW_part,
                                            part_s, part_ctx);
    else
      k_attn<0><<<B_*NSL, 256, 0, stream>>>(x, x_f8, uxpb, Va, hW_part,
                                            part_s, part_ctx);
    if (use_wbf)
      k_step<1><<<B_*8, 256, 0, stream>>>(Wk, Wr, wk_bf, wr_bf, bs, Wa, wa_bf,
                                          part_s, part_ctx, h_in, h_out,
                                          c_ws, hW_part, (float*)d_out, s, TDEC);
    else
      k_step<0><<<B_*8, 256, 0, stream>>>(Wk, Wr, wk_bf, wr_bf, bs, Wa, wa_bf,
                                          part_s, part_ctx, h_in, h_out,
                                          c_ws, hW_part, (float*)d_out, s, TDEC);
  }
}